// Round 6
// baseline (672.586 us; speedup 1.0000x reference)
//
#include <hip/hip_runtime.h>

// ct_layer round 6: wide wave tiles (64co x 128n) to halve weight-stream
// traffic per FLOP (A-fragment L1/L2 bandwidth was pinning MfmaUtil at 37%).
//   - pool identity: s = u[w] + v[h]; conv_p separable -> uv1d GEMMs.
//   - p12: set0 tile 8h x 16w (in-lane max over h -> u atomics);
//          set1 tile 16h x 8w, transposed halo (in-lane max over w -> v).
//   - block = 256co x 128n, 4 waves = 4 co-slices, 2 blocks/CU.

typedef _Float16 f16x8 __attribute__((ext_vector_type(8)));
typedef _Float16 f16x4v __attribute__((ext_vector_type(4)));
typedef float f32x4 __attribute__((ext_vector_type(4)));

#define HP 98
#define WP 98
#define KTOT 2304
#define WSET (256*KTOT)                // 589824 elems per weight set
#define XPAD_E ((size_t)8*HP*WP*256)
#define UVP_E  ((size_t)8*98*256)      // u_pad/v_pad f32 (atomic targets)
#define UV2_E  ((size_t)3*8*96*256)    // u2/v2 f32 [case][b][pos][co]
#define WUV_SET 196608                 // 256co * 768k per (t,case)

#define BUF_B 12288                    // staged ci-slice: 192 pos * 64B (180 valid)
#define SMEM_B 24576                   // double buffer

struct Ctx {
  unsigned goff[3];
  unsigned lds_stage;
  unsigned aoff;                       // (wv*4)*512 + wl*32 + quad*8
  int wl, quad, wv;
  int b, h0, w0;
};

// TR=0: tile 8h x 16w, halo 10x18, lane dim = w, j = h
// TR=1: tile 16h x 8w, halo 18x10, lane dim = h, j = w
template<int TR>
__device__ __forceinline__ Ctx make_ctx(int spatial)
{
  Ctx c;
  c.b = spatial / 72;
  const int tt = spatial - c.b * 72;
  if (TR == 0) { const int ht = tt / 6,  wt = tt - ht * 6;  c.h0 = ht * 8;  c.w0 = wt * 16; }
  else         { const int ht = tt / 12, wt = tt - ht * 12; c.h0 = ht * 16; c.w0 = wt * 8;  }
  const int tid = threadIdx.x, lane = tid & 63;
  c.wv = tid >> 6;
  c.quad = lane >> 4; c.wl = lane & 15;
  c.aoff = (unsigned)(c.wv * 4 * 512 + c.wl * 32 + c.quad * 8);
  const unsigned base_hw = (unsigned)(c.b * HP + c.h0) * WP + c.w0;
#pragma unroll
  for (int t = 0; t < 3; ++t) {
    int pos = (c.wv * 3 + t) * 16 + (lane >> 2);   // 0..191; 180..191 dummy
    if (pos > 179) pos = 179;
    const int wh = (TR == 0) ? pos / 18 : pos / 10;
    const int ww = (TR == 0) ? pos - wh * 18 : pos - wh * 10;
    c.goff[t] = (base_hw + (unsigned)(wh * WP + ww)) * 256u + (lane & 3) * 8u;
  }
  c.lds_stage = (unsigned)(c.wv * 3) * 1024u + (unsigned)lane * 16u;
  return c;
}

__device__ __forceinline__ void stage_cb(const _Float16* __restrict__ src,
                                         char* sbuf, const Ctx& c, int buf, int cb)
{
  char* l0 = sbuf + buf * BUF_B + c.lds_stage;
#pragma unroll
  for (int t = 0; t < 3; ++t) {
    const _Float16* g = src + c.goff[t] + cb * 32;
    __builtin_amdgcn_global_load_lds(
        (const __attribute__((address_space(1))) void*)g,
        (__attribute__((address_space(3))) void*)(l0 + t * 1024), 16, 0, 0);
  }
}

// Full conv accumulation (K = 9 taps x 256 ci) into acc[4][8].
// Weight tile layout: idx = ((cb*9+tap)*16 + cog)*512 + m*32 + kk.
template<int TR>
__device__ __forceinline__ void conv_accum(const _Float16* __restrict__ src,
                                           const _Float16* __restrict__ wkb,
                                           char* sbuf, const Ctx& c, f32x4 acc[4][8])
{
  const _Float16* A0 = wkb + c.aoff;
  stage_cb(src, sbuf, c, 0, 0);
#pragma unroll 1
  for (int cb = 0; cb < 8; ++cb) {
    __syncthreads();
    if (cb < 7) stage_cb(src, sbuf, c, (cb + 1) & 1, cb + 1);
    const _Float16* B = (const _Float16*)(sbuf + (cb & 1) * BUF_B);
    const _Float16* A = A0 + cb * (9 * 8192);
#pragma unroll
    for (int o = 0; o < 3; ++o) {                  // TR0: o=dw ; TR1: o=dh
      f16x8 cache[10];
#pragma unroll
      for (int r = 0; r < 10; ++r)
        cache[r] = (TR == 0)
            ? *(const f16x8*)(B + (r * 18 + c.wl + o) * 32 + c.quad * 8)
            : *(const f16x8*)(B + ((c.wl + o) * 10 + r) * 32 + c.quad * 8);
#pragma unroll
      for (int p = 0; p < 3; ++p) {                // TR0: p=dh ; TR1: p=dw
        const int tap = (TR == 0) ? p * 3 + o : o * 3 + p;
        f16x8 af[4];
#pragma unroll
        for (int i = 0; i < 4; ++i)
          af[i] = *(const f16x8*)(A + tap * 8192 + i * 512);
#pragma unroll
        for (int i = 0; i < 4; ++i)
#pragma unroll
          for (int j = 0; j < 8; ++j)
            acc[i][j] = __builtin_amdgcn_mfma_f32_16x16x32_f16(af[i], cache[j + p], acc[i][j], 0, 0, 0);
      }
    }
  }
  __syncthreads();
}

#define ZERO_ACC(acc) \
  _Pragma("unroll") for (int i = 0; i < 4; ++i) \
  _Pragma("unroll") for (int j = 0; j < 8; ++j) acc[i][j] = (f32x4){0.f,0.f,0.f,0.f};

// ---------------- p12: conv -> relu -> axis max -> atomicMax --------------
__global__ __launch_bounds__(256, 2) void k_conv_p12(
    const _Float16* __restrict__ xpad, const _Float16* __restrict__ wk,
    const float* __restrict__ bias1, const float* __restrict__ bias2,
    float* __restrict__ u_pad, float* __restrict__ v_pad)
{
  __shared__ __align__(16) char smem[SMEM_B];
  const int lin = blockIdx.x;
  const int set = lin >= 576;
  const int spatial = lin - set * 576;
  f32x4 acc[4][8];
  ZERO_ACC(acc)
  if (set == 0) {
    Ctx c = make_ctx<0>(spatial);
    conv_accum<0>(xpad, wk, smem, c, acc);
#pragma unroll
    for (int i = 0; i < 4; ++i) {
      const int co = c.wv * 64 + i * 16 + c.quad * 4;
      const float4 bs = *(const float4*)(bias1 + co);
      float m0 = 0.f, m1 = 0.f, m2 = 0.f, m3 = 0.f;
#pragma unroll
      for (int j = 0; j < 8; ++j) {                // j = h: in-lane max over h
        m0 = fmaxf(m0, acc[i][j][0] + bs.x);
        m1 = fmaxf(m1, acc[i][j][1] + bs.y);
        m2 = fmaxf(m2, acc[i][j][2] + bs.z);
        m3 = fmaxf(m3, acc[i][j][3] + bs.w);
      }
      unsigned* tgt = (unsigned*)(u_pad + ((size_t)c.b * 98 + (c.w0 + c.wl + 1)) * 256 + co);
      atomicMax(tgt + 0, __float_as_uint(m0));
      atomicMax(tgt + 1, __float_as_uint(m1));
      atomicMax(tgt + 2, __float_as_uint(m2));
      atomicMax(tgt + 3, __float_as_uint(m3));
    }
  } else {
    Ctx c = make_ctx<1>(spatial);
    conv_accum<1>(xpad, wk + WSET, smem, c, acc);
#pragma unroll
    for (int i = 0; i < 4; ++i) {
      const int co = c.wv * 64 + i * 16 + c.quad * 4;
      const float4 bs = *(const float4*)(bias2 + co);
      float m0 = 0.f, m1 = 0.f, m2 = 0.f, m3 = 0.f;
#pragma unroll
      for (int j = 0; j < 8; ++j) {                // j = w: in-lane max over w
        m0 = fmaxf(m0, acc[i][j][0] + bs.x);
        m1 = fmaxf(m1, acc[i][j][1] + bs.y);
        m2 = fmaxf(m2, acc[i][j][2] + bs.z);
        m3 = fmaxf(m3, acc[i][j][3] + bs.w);
      }
      unsigned* tgt = (unsigned*)(v_pad + ((size_t)c.b * 98 + (c.h0 + c.wl + 1)) * 256 + co);
      atomicMax(tgt + 0, __float_as_uint(m0));
      atomicMax(tgt + 1, __float_as_uint(m1));
      atomicMax(tgt + 2, __float_as_uint(m2));
      atomicMax(tgt + 3, __float_as_uint(m3));
    }
  }
}

// ---------------- 1D convs of u,v with case-summed weights ----------------
__global__ __launch_bounds__(256, 2) void k_uv1d(
    const float* __restrict__ u_pad, const float* __restrict__ v_pad,
    const _Float16* __restrict__ wuv, float* __restrict__ u2, float* __restrict__ v2)
{
  const int id = blockIdx.x;
  const int b = id & 7, cs = (id >> 3) % 3, t = id / 24;
  const float* src = t ? v_pad : u_pad;
  float* dst = t ? v2 : u2;
  const _Float16* A0 = wuv + (size_t)(t * 3 + cs) * WUV_SET;
  const int lane = threadIdx.x & 63, wv = threadIdx.x >> 6;
  const int quad = lane >> 4, l16 = lane & 15;

  f32x4 acc[4][6];
#pragma unroll
  for (int i = 0; i < 4; ++i)
#pragma unroll
    for (int j = 0; j < 6; ++j) acc[i][j] = (f32x4){0.f, 0.f, 0.f, 0.f};

#pragma unroll 1
  for (int kb = 0; kb < 24; ++kb) {
    const int dw = kb >> 3, cb = kb & 7;
    f16x8 bf[6];
#pragma unroll
    for (int j = 0; j < 6; ++j) {
      const int pos = j * 16 + l16;
      const float* p = src + ((size_t)b * 98 + (pos + dw)) * 256 + cb * 32 + quad * 8;
      const float4 x0 = *(const float4*)p;
      const float4 x1 = *(const float4*)(p + 4);
      f16x8 v;
      v[0] = (_Float16)x0.x; v[1] = (_Float16)x0.y; v[2] = (_Float16)x0.z; v[3] = (_Float16)x0.w;
      v[4] = (_Float16)x1.x; v[5] = (_Float16)x1.y; v[6] = (_Float16)x1.z; v[7] = (_Float16)x1.w;
      bf[j] = v;
    }
    f16x8 af[4];
#pragma unroll
    for (int i = 0; i < 4; ++i)
      af[i] = *(const f16x8*)(A0 + (size_t)(kb * 16 + wv * 4 + i) * 512 + l16 * 32 + quad * 8);
#pragma unroll
    for (int i = 0; i < 4; ++i)
#pragma unroll
      for (int j = 0; j < 6; ++j)
        acc[i][j] = __builtin_amdgcn_mfma_f32_16x16x32_f16(af[i], bf[j], acc[i][j], 0, 0, 0);
  }
#pragma unroll
  for (int i = 0; i < 4; ++i)
#pragma unroll
    for (int j = 0; j < 6; ++j) {
      const int pos = j * 16 + l16;
      const int co = wv * 64 + i * 16 + quad * 4;
      *(f32x4*)(dst + ((size_t)(cs * 8 + b) * 96 + pos) * 256 + co) = acc[i][j];
    }
}

// ---------------- conv_c1 + U' + V' + biases, relu -> r_pad NHWC f16 ------
__global__ __launch_bounds__(256, 2) void k_conv_c1f(
    const _Float16* __restrict__ xpad, const _Float16* __restrict__ wkc1,
    const float* __restrict__ bias_p, const float* __restrict__ bias_c1,
    const float* __restrict__ u2, const float* __restrict__ v2,
    _Float16* __restrict__ rpad)
{
  __shared__ __align__(16) char smem[SMEM_B];
  Ctx c = make_ctx<0>(blockIdx.x);
  f32x4 acc[4][8];
  ZERO_ACC(acc)
  conv_accum<0>(xpad, wkc1, smem, c, acc);

  const int w = c.w0 + c.wl;
  const int wcase = (w == 0) ? 0 : ((w == 95) ? 2 : 1);
#pragma unroll
  for (int i = 0; i < 4; ++i) {
    const int co = c.wv * 64 + i * 16 + c.quad * 4;
    float4 bs = *(const float4*)(bias_p + co);
    const float4 b2 = *(const float4*)(bias_c1 + co);
    bs.x += b2.x; bs.y += b2.y; bs.z += b2.z; bs.w += b2.w;
#pragma unroll
    for (int j = 0; j < 8; ++j) {
      const int h = c.h0 + j;
      const int hcase = (h == 0) ? 0 : ((h == 95) ? 2 : 1);
      const float4 uq = *(const float4*)(u2 + ((size_t)(hcase * 8 + c.b) * 96 + w) * 256 + co);
      const float4 vq = *(const float4*)(v2 + ((size_t)(wcase * 8 + c.b) * 96 + h) * 256 + co);
      f16x4v pk;
      pk[0] = (_Float16)fmaxf(acc[i][j][0] + bs.x + uq.x + vq.x, 0.f);
      pk[1] = (_Float16)fmaxf(acc[i][j][1] + bs.y + uq.y + vq.y, 0.f);
      pk[2] = (_Float16)fmaxf(acc[i][j][2] + bs.z + uq.z + vq.z, 0.f);
      pk[3] = (_Float16)fmaxf(acc[i][j][3] + bs.w + uq.w + vq.w, 0.f);
      *(f16x4v*)(rpad + ((size_t)(c.b * HP + c.h0 + j + 1) * WP + (w + 1)) * 256 + co) = pk;
    }
  }
}

// ---------------- final conv, relu, NCHW f32 to d_out ---------------------
__global__ __launch_bounds__(256, 2) void k_conv_c2(
    const _Float16* __restrict__ rpad, const _Float16* __restrict__ wkc2,
    const float* __restrict__ bias, float* __restrict__ dout)
{
  __shared__ __align__(16) char smem[SMEM_B];
  Ctx c = make_ctx<0>(blockIdx.x);
  f32x4 acc[4][8];
  ZERO_ACC(acc)
  conv_accum<0>(rpad, wkc2, smem, c, acc);
  const int w = c.w0 + c.wl;
#pragma unroll
  for (int i = 0; i < 4; ++i) {
    const int co = c.wv * 64 + i * 16 + c.quad * 4;
    const float4 bs = *(const float4*)(bias + co);
#pragma unroll
    for (int j = 0; j < 8; ++j) {
      float* op = dout + (size_t)c.b * 2359296 + (c.h0 + j) * 96 + w;
      op[(size_t)(co + 0) * 9216] = fmaxf(acc[i][j][0] + bs.x, 0.f);
      op[(size_t)(co + 1) * 9216] = fmaxf(acc[i][j][1] + bs.y, 0.f);
      op[(size_t)(co + 2) * 9216] = fmaxf(acc[i][j][2] + bs.z, 0.f);
      op[(size_t)(co + 3) * 9216] = fmaxf(acc[i][j][3] + bs.w, 0.f);
    }
  }
}

// ---------------- aux kernels ---------------------------------------------
__global__ void k_pack_x(const float* __restrict__ x, _Float16* __restrict__ xpad)
{
  __shared__ float tile[32][33];
  const int bh = blockIdx.x;
  const int b = bh / 96, h = bh - b * 96;
  const int c0 = blockIdx.y * 32, w0 = blockIdx.z * 32;
  const int tx = threadIdx.x & 31, ty = threadIdx.x >> 5;
#pragma unroll
  for (int i = 0; i < 4; ++i) {
    int cI = c0 + ty + i * 8;
    tile[ty + i * 8][tx] = x[(((size_t)b * 256 + cI) * 96 + h) * 96 + w0 + tx];
  }
  __syncthreads();
#pragma unroll
  for (int i = 0; i < 4; ++i) {
    int w = w0 + ty + i * 8;
    xpad[((size_t)(b * HP + h + 1) * WP + (w + 1)) * 256 + c0 + tx] =
        (_Float16)tile[tx][ty + i * 8];
  }
}

// main conv weights -> tiled layout: idx = ((cb*9+tap)*16 + cog)*512 + m*32 + kk
__global__ void k_repack_w(const float* w0, const float* g0, const float* w1, const float* g1,
                           const float* w2, const float* g2, const float* w3, const float* g3,
                           const float* w4, const float* g4, _Float16* __restrict__ wk)
{
  const int set = blockIdx.y;
  const float* w; const float* g;
  switch (set) {
    case 0: w = w0; g = g0; break;
    case 1: w = w1; g = g1; break;
    case 2: w = w2; g = g2; break;
    case 3: w = w3; g = g3; break;
    default: w = w4; g = g4; break;
  }
  const int t = blockIdx.x * 256 + threadIdx.x;   // co*256 + ci
  const int co = t >> 8, ci = t & 255;
  const int cb = ci >> 5, kk = ci & 31, cog = co >> 4, m = co & 15;
  const float gv = g[co];
  const float* src = w + ((size_t)co * 256 + ci) * 9;
  _Float16* dst = wk + (size_t)set * WSET + cog * 512 + m * 32 + kk;
#pragma unroll
  for (int tap = 0; tap < 9; ++tap)
    dst[(cb * 9 + tap) * 8192] = (_Float16)(src[tap] * gv);
}

// case-summed 1D weights for U'/V'
__global__ void k_repack_uvw(const float* __restrict__ wp, const float* __restrict__ gp,
                             _Float16* __restrict__ wuv)
{
  const int tcs = blockIdx.y;                             // 0..5 = t*3+cs
  const int tt = tcs / 3, cs = tcs - tt * 3;
  const int idx = blockIdx.x * 256 + threadIdx.x;         // co*256 + ci
  const int co = idx >> 8, ci = idx & 255;
  const float gv = gp[co];
  const float* src = wp + ((size_t)co * 256 + ci) * 9;    // [dh][dw]
  const int lo = (cs == 0) ? 1 : 0, hi = (cs == 2) ? 1 : 2;
  _Float16* base = wuv + (size_t)tcs * WUV_SET;
#pragma unroll
  for (int d = 0; d < 3; ++d) {
    float s = 0.f;
    for (int e = lo; e <= hi; ++e)
      s += (tt == 0) ? src[e * 3 + d] : src[d * 3 + e];
    const int k = d * 256 + ci;
    const int kb = k >> 5, kk = k & 31;
    base[(size_t)(kb * 16 + (co >> 4)) * 512 + (co & 15) * 32 + kk] = (_Float16)(s * gv);
  }
}

// ---------------- launcher -------------------------------------------------
extern "C" void kernel_launch(void* const* d_in, const int* in_sizes, int n_in,
                              void* d_out, int out_size, void* d_ws, size_t ws_size,
                              hipStream_t stream)
{
  const float* x    = (const float*)d_in[0];
  const float* w_p1 = (const float*)d_in[1];
  const float* g_p1 = (const float*)d_in[2];
  const float* b_p1 = (const float*)d_in[3];
  const float* w_p2 = (const float*)d_in[4];
  const float* g_p2 = (const float*)d_in[5];
  const float* b_p2 = (const float*)d_in[6];
  const float* w_p  = (const float*)d_in[7];
  const float* g_p  = (const float*)d_in[8];
  const float* b_p  = (const float*)d_in[9];
  const float* w_c1 = (const float*)d_in[10];
  const float* g_c1 = (const float*)d_in[11];
  const float* b_c1 = (const float*)d_in[12];
  const float* w_c2 = (const float*)d_in[13];
  const float* g_c2 = (const float*)d_in[14];
  const float* b_c2 = (const float*)d_in[15];

  char* ws = (char*)d_ws;
  size_t off = 0;
  _Float16* x_pad = (_Float16*)(ws + off); off += XPAD_E * 2;
  _Float16* r_pad = (_Float16*)(ws + off); off += XPAD_E * 2;
  _Float16* wks   = (_Float16*)(ws + off); off += (size_t)5 * WSET * 2;
  _Float16* wuv   = (_Float16*)(ws + off); off += (size_t)6 * WUV_SET * 2;
  float*    u_pad = (float*)(ws + off);    off += UVP_E * 4;
  float*    v_pad = (float*)(ws + off);    off += UVP_E * 4;
  float*    u2    = (float*)(ws + off);    off += UV2_E * 4;
  float*    v2    = (float*)(ws + off);    off += UV2_E * 4;
  (void)ws_size; (void)in_sizes; (void)n_in; (void)out_size;

  hipMemsetAsync(x_pad, 0, XPAD_E * 2, stream);
  hipMemsetAsync(r_pad, 0, XPAD_E * 2, stream);
  hipMemsetAsync(u_pad, 0, UVP_E * 4, stream);
  hipMemsetAsync(v_pad, 0, UVP_E * 4, stream);

  k_pack_x    <<<dim3(768, 8, 3), 256, 0, stream>>>(x, x_pad);
  k_repack_w  <<<dim3(256, 5),    256, 0, stream>>>(w_p1, g_p1, w_p2, g_p2, w_p, g_p,
                                                    w_c1, g_c1, w_c2, g_c2, wks);
  k_repack_uvw<<<dim3(256, 6),    256, 0, stream>>>(w_p, g_p, wuv);
  k_conv_p12  <<<1152, 256, 0, stream>>>(x_pad, wks, b_p1, b_p2, u_pad, v_pad);
  k_uv1d      <<<48,   256, 0, stream>>>(u_pad, v_pad, wuv, u2, v2);
  k_conv_c1f  <<<576,  256, 0, stream>>>(x_pad, wks + (size_t)3 * WSET, b_p, b_c1,
                                         u2, v2, r_pad);
  k_conv_c2   <<<576,  256, 0, stream>>>(r_pad, wks + (size_t)4 * WSET, b_c2,
                                         (float*)d_out);
}

// Round 7
// 639.088 us; speedup vs baseline: 1.0524x; 1.0524x over previous
//
#include <hip/hip_runtime.h>

// ct_layer round 7: consolidation.
//   - pool identity: s = u[w] + v[h]; conv_p separable -> uv1d GEMMs.
//   - p12 (R6 best): wide waves 64co x 128n, TR0/TR1 tiles, in-register axis
//     max -> atomicMax into u_pad/v_pad.
//   - c1f/c2 (R5 best): 64co x 256n shared-weight blocks, occupancy 3.
//   - border kernel replaces 2x38MB memsets (only halos need zeroing).

typedef _Float16 f16x8 __attribute__((ext_vector_type(8)));
typedef _Float16 f16x4v __attribute__((ext_vector_type(4)));
typedef float f32x4 __attribute__((ext_vector_type(4)));

#define HP 98
#define WP 98
#define KTOT 2304
#define WSET (256*KTOT)                // 589824 elems per weight set
#define XPAD_E ((size_t)8*HP*WP*256)
#define UVP_E  ((size_t)8*98*256)      // u_pad/v_pad f32 (atomic targets)
#define UV2_E  ((size_t)3*8*96*256)    // u2/v2 f32 [case][b][pos][co]
#define WUV_SET 196608                 // 256co * 768k per (t,case)

// ---------------- wide-wave conv core (p12): 64co x 128n per wave ---------
#define BUF_B 12288                    // staged ci-slice: 192 pos * 64B
#define SMEM_B 24576

struct Ctx {
  unsigned goff[3];
  unsigned lds_stage;
  unsigned aoff;
  int wl, quad, wv;
  int b, h0, w0;
};

// TR=0: tile 8h x 16w, halo 10x18, lane dim = w, j = h
// TR=1: tile 16h x 8w, halo 18x10, lane dim = h, j = w
template<int TR>
__device__ __forceinline__ Ctx make_ctx(int spatial)
{
  Ctx c;
  c.b = spatial / 72;
  const int tt = spatial - c.b * 72;
  if (TR == 0) { const int ht = tt / 6,  wt = tt - ht * 6;  c.h0 = ht * 8;  c.w0 = wt * 16; }
  else         { const int ht = tt / 12, wt = tt - ht * 12; c.h0 = ht * 16; c.w0 = wt * 8;  }
  const int tid = threadIdx.x, lane = tid & 63;
  c.wv = tid >> 6;
  c.quad = lane >> 4; c.wl = lane & 15;
  c.aoff = (unsigned)(c.wv * 4 * 512 + c.wl * 32 + c.quad * 8);
  const unsigned base_hw = (unsigned)(c.b * HP + c.h0) * WP + c.w0;
#pragma unroll
  for (int t = 0; t < 3; ++t) {
    int pos = (c.wv * 3 + t) * 16 + (lane >> 2);   // 0..191; 180..191 dummy
    if (pos > 179) pos = 179;
    const int wh = (TR == 0) ? pos / 18 : pos / 10;
    const int ww = (TR == 0) ? pos - wh * 18 : pos - wh * 10;
    c.goff[t] = (base_hw + (unsigned)(wh * WP + ww)) * 256u + (lane & 3) * 8u;
  }
  c.lds_stage = (unsigned)(c.wv * 3) * 1024u + (unsigned)lane * 16u;
  return c;
}

__device__ __forceinline__ void stage_cb(const _Float16* __restrict__ src,
                                         char* sbuf, const Ctx& c, int buf, int cb)
{
  char* l0 = sbuf + buf * BUF_B + c.lds_stage;
#pragma unroll
  for (int t = 0; t < 3; ++t) {
    const _Float16* g = src + c.goff[t] + cb * 32;
    __builtin_amdgcn_global_load_lds(
        (const __attribute__((address_space(1))) void*)g,
        (__attribute__((address_space(3))) void*)(l0 + t * 1024), 16, 0, 0);
  }
}

// Weight tile layout: idx = ((cb*9+tap)*16 + cog)*512 + m*32 + kk.
template<int TR>
__device__ __forceinline__ void conv_accum(const _Float16* __restrict__ src,
                                           const _Float16* __restrict__ wkb,
                                           char* sbuf, const Ctx& c, f32x4 acc[4][8])
{
  const _Float16* A0 = wkb + c.aoff;
  stage_cb(src, sbuf, c, 0, 0);
#pragma unroll 1
  for (int cb = 0; cb < 8; ++cb) {
    __syncthreads();
    if (cb < 7) stage_cb(src, sbuf, c, (cb + 1) & 1, cb + 1);
    const _Float16* B = (const _Float16*)(sbuf + (cb & 1) * BUF_B);
    const _Float16* A = A0 + cb * (9 * 8192);
#pragma unroll
    for (int o = 0; o < 3; ++o) {                  // TR0: o=dw ; TR1: o=dh
      f16x8 cache[10];
#pragma unroll
      for (int r = 0; r < 10; ++r)
        cache[r] = (TR == 0)
            ? *(const f16x8*)(B + (r * 18 + c.wl + o) * 32 + c.quad * 8)
            : *(const f16x8*)(B + ((c.wl + o) * 10 + r) * 32 + c.quad * 8);
#pragma unroll
      for (int p = 0; p < 3; ++p) {                // TR0: p=dh ; TR1: p=dw
        const int tap = (TR == 0) ? p * 3 + o : o * 3 + p;
        f16x8 af[4];
#pragma unroll
        for (int i = 0; i < 4; ++i)
          af[i] = *(const f16x8*)(A + tap * 8192 + i * 512);
#pragma unroll
        for (int i = 0; i < 4; ++i)
#pragma unroll
          for (int j = 0; j < 8; ++j)
            acc[i][j] = __builtin_amdgcn_mfma_f32_16x16x32_f16(af[i], cache[j + p], acc[i][j], 0, 0, 0);
      }
    }
  }
  __syncthreads();
}

#define ZERO_ACC8(acc) \
  _Pragma("unroll") for (int i = 0; i < 4; ++i) \
  _Pragma("unroll") for (int j = 0; j < 8; ++j) acc[i][j] = (f32x4){0.f,0.f,0.f,0.f};

// ---------------- shared-weight conv core (c1f/c2): 64co x 256n block -----
#define BUF_BS 24576                   // staged ci-slice: 384 pos * 64B (324 valid)
#define SMEM_BS 49152                  // 2*BUF_BS; epilogue lt needs 256*68*2

struct CtxS {
  unsigned goff[6];
  unsigned lds_stage;
  unsigned aoff;
  int hl, wl, quad;
  int co_wg;
  int b, h0, w0;
};

__device__ __forceinline__ CtxS make_ctxS(int spatial, int co_wg)
{
  CtxS c;
  c.co_wg = co_wg;
  c.b = spatial / 36;
  const int tt = spatial - c.b * 36;
  const int ht = tt / 6, wt = tt - ht * 6;
  c.h0 = ht * 16; c.w0 = wt * 16;
  const int tid = threadIdx.x, lane = tid & 63, wv = tid >> 6;
  c.quad = lane >> 4; c.wl = lane & 15;
  c.hl = wv * 4;
  c.aoff = (unsigned)(c.wl * 32 + c.quad * 8);
  const unsigned base_hw = (unsigned)(c.b * HP + c.h0) * WP + c.w0;
#pragma unroll
  for (int t = 0; t < 6; ++t) {
    int pos = (wv * 6 + t) * 16 + (lane >> 2);   // 0..383; 324..383 dummy
    if (pos > 323) pos = 323;
    const int wh = pos / 18, ww = pos - wh * 18;
    c.goff[t] = (base_hw + (unsigned)(wh * WP + ww)) * 256u + (lane & 3) * 8u;
  }
  c.lds_stage = (unsigned)(wv * 6) * 1024u + (unsigned)lane * 16u;
  return c;
}

__device__ __forceinline__ void stage_cbS(const _Float16* __restrict__ src,
                                          char* sbuf, const CtxS& c, int buf, int cb)
{
  char* l0 = sbuf + buf * BUF_BS + c.lds_stage;
#pragma unroll
  for (int t = 0; t < 6; ++t) {
    const _Float16* g = src + c.goff[t] + cb * 32;
    __builtin_amdgcn_global_load_lds(
        (const __attribute__((address_space(1))) void*)g,
        (__attribute__((address_space(3))) void*)(l0 + t * 1024), 16, 0, 0);
  }
}

__device__ __forceinline__ void conv_accumS(const _Float16* __restrict__ src,
                                            const _Float16* __restrict__ wkb,
                                            char* sbuf, const CtxS& c,
                                            f32x4 acc[4][4])
{
  const _Float16* A0 = wkb + c.aoff;
  const int rbase = (c.hl * 18 + c.wl) * 32 + c.quad * 8;
  stage_cbS(src, sbuf, c, 0, 0);
#pragma unroll 1
  for (int cb = 0; cb < 8; ++cb) {
    __syncthreads();
    if (cb < 7) stage_cbS(src, sbuf, c, (cb + 1) & 1, cb + 1);
    const _Float16* B = (const _Float16*)(sbuf + (cb & 1) * BUF_BS);
    const _Float16* A = A0 + cb * (9 * 8192);
#pragma unroll
    for (int dw = 0; dw < 3; ++dw) {
      f16x8 row[6];
#pragma unroll
      for (int r = 0; r < 6; ++r)
        row[r] = *(const f16x8*)(B + rbase + (r * 18 + dw) * 32);
#pragma unroll
      for (int dh = 0; dh < 3; ++dh) {
        f16x8 af[4];
#pragma unroll
        for (int i = 0; i < 4; ++i)
          af[i] = *(const f16x8*)(A + (dh * 3 + dw) * 8192 + i * 512);
#pragma unroll
        for (int i = 0; i < 4; ++i)
#pragma unroll
          for (int j = 0; j < 4; ++j)
            acc[i][j] = __builtin_amdgcn_mfma_f32_16x16x32_f16(af[i], row[j + dh], acc[i][j], 0, 0, 0);
      }
    }
  }
  __syncthreads();
}

// ---------------- p12: conv -> relu -> axis max -> atomicMax --------------
__global__ __launch_bounds__(256, 2) void k_conv_p12(
    const _Float16* __restrict__ xpad, const _Float16* __restrict__ wk,
    const float* __restrict__ bias1, const float* __restrict__ bias2,
    float* __restrict__ u_pad, float* __restrict__ v_pad)
{
  __shared__ __align__(16) char smem[SMEM_B];
  const int lin = blockIdx.x;
  const int set = lin >= 576;
  const int spatial = lin - set * 576;
  f32x4 acc[4][8];
  ZERO_ACC8(acc)
  if (set == 0) {
    Ctx c = make_ctx<0>(spatial);
    conv_accum<0>(xpad, wk, smem, c, acc);
#pragma unroll
    for (int i = 0; i < 4; ++i) {
      const int co = c.wv * 64 + i * 16 + c.quad * 4;
      const float4 bs = *(const float4*)(bias1 + co);
      float m0 = 0.f, m1 = 0.f, m2 = 0.f, m3 = 0.f;
#pragma unroll
      for (int j = 0; j < 8; ++j) {                // j = h: in-lane max over h
        m0 = fmaxf(m0, acc[i][j][0] + bs.x);
        m1 = fmaxf(m1, acc[i][j][1] + bs.y);
        m2 = fmaxf(m2, acc[i][j][2] + bs.z);
        m3 = fmaxf(m3, acc[i][j][3] + bs.w);
      }
      unsigned* tgt = (unsigned*)(u_pad + ((size_t)c.b * 98 + (c.w0 + c.wl + 1)) * 256 + co);
      atomicMax(tgt + 0, __float_as_uint(m0));
      atomicMax(tgt + 1, __float_as_uint(m1));
      atomicMax(tgt + 2, __float_as_uint(m2));
      atomicMax(tgt + 3, __float_as_uint(m3));
    }
  } else {
    Ctx c = make_ctx<1>(spatial);
    conv_accum<1>(xpad, wk + WSET, smem, c, acc);
#pragma unroll
    for (int i = 0; i < 4; ++i) {
      const int co = c.wv * 64 + i * 16 + c.quad * 4;
      const float4 bs = *(const float4*)(bias2 + co);
      float m0 = 0.f, m1 = 0.f, m2 = 0.f, m3 = 0.f;
#pragma unroll
      for (int j = 0; j < 8; ++j) {                // j = w: in-lane max over w
        m0 = fmaxf(m0, acc[i][j][0] + bs.x);
        m1 = fmaxf(m1, acc[i][j][1] + bs.y);
        m2 = fmaxf(m2, acc[i][j][2] + bs.z);
        m3 = fmaxf(m3, acc[i][j][3] + bs.w);
      }
      unsigned* tgt = (unsigned*)(v_pad + ((size_t)c.b * 98 + (c.h0 + c.wl + 1)) * 256 + co);
      atomicMax(tgt + 0, __float_as_uint(m0));
      atomicMax(tgt + 1, __float_as_uint(m1));
      atomicMax(tgt + 2, __float_as_uint(m2));
      atomicMax(tgt + 3, __float_as_uint(m3));
    }
  }
}

// ---------------- 1D convs of u,v with case-summed weights ----------------
__global__ __launch_bounds__(256, 2) void k_uv1d(
    const float* __restrict__ u_pad, const float* __restrict__ v_pad,
    const _Float16* __restrict__ wuv, float* __restrict__ u2, float* __restrict__ v2)
{
  const int id = blockIdx.x;
  const int b = id & 7, cs = (id >> 3) % 3, t = id / 24;
  const float* src = t ? v_pad : u_pad;
  float* dst = t ? v2 : u2;
  const _Float16* A0 = wuv + (size_t)(t * 3 + cs) * WUV_SET;
  const int lane = threadIdx.x & 63, wv = threadIdx.x >> 6;
  const int quad = lane >> 4, l16 = lane & 15;

  f32x4 acc[4][6];
#pragma unroll
  for (int i = 0; i < 4; ++i)
#pragma unroll
    for (int j = 0; j < 6; ++j) acc[i][j] = (f32x4){0.f, 0.f, 0.f, 0.f};

#pragma unroll 1
  for (int kb = 0; kb < 24; ++kb) {
    const int dw = kb >> 3, cb = kb & 7;
    f16x8 bf[6];
#pragma unroll
    for (int j = 0; j < 6; ++j) {
      const int pos = j * 16 + l16;
      const float* p = src + ((size_t)b * 98 + (pos + dw)) * 256 + cb * 32 + quad * 8;
      const float4 x0 = *(const float4*)p;
      const float4 x1 = *(const float4*)(p + 4);
      f16x8 v;
      v[0] = (_Float16)x0.x; v[1] = (_Float16)x0.y; v[2] = (_Float16)x0.z; v[3] = (_Float16)x0.w;
      v[4] = (_Float16)x1.x; v[5] = (_Float16)x1.y; v[6] = (_Float16)x1.z; v[7] = (_Float16)x1.w;
      bf[j] = v;
    }
    f16x8 af[4];
#pragma unroll
    for (int i = 0; i < 4; ++i)
      af[i] = *(const f16x8*)(A0 + (size_t)(kb * 16 + wv * 4 + i) * 512 + l16 * 32 + quad * 8);
#pragma unroll
    for (int i = 0; i < 4; ++i)
#pragma unroll
      for (int j = 0; j < 6; ++j)
        acc[i][j] = __builtin_amdgcn_mfma_f32_16x16x32_f16(af[i], bf[j], acc[i][j], 0, 0, 0);
  }
#pragma unroll
  for (int i = 0; i < 4; ++i)
#pragma unroll
    for (int j = 0; j < 6; ++j) {
      const int pos = j * 16 + l16;
      const int co = wv * 64 + i * 16 + quad * 4;
      *(f32x4*)(dst + ((size_t)(cs * 8 + b) * 96 + pos) * 256 + co) = acc[i][j];
    }
}

// ---------------- conv_c1 + U' + V' + biases, relu -> r_pad NHWC f16 ------
__global__ __launch_bounds__(256, 3) void k_conv_c1f(
    const _Float16* __restrict__ xpad, const _Float16* __restrict__ wkc1,
    const float* __restrict__ bias_p, const float* __restrict__ bias_c1,
    const float* __restrict__ u2, const float* __restrict__ v2,
    _Float16* __restrict__ rpad)
{
  __shared__ __align__(16) char smem[SMEM_BS];
  const int lin = blockIdx.x;
  const int co_blk = lin / 288, spatial = lin - co_blk * 288;
  CtxS c = make_ctxS(spatial, co_blk * 64);
  f32x4 acc[4][4];
#pragma unroll
  for (int i = 0; i < 4; ++i)
#pragma unroll
    for (int j = 0; j < 4; ++j) acc[i][j] = (f32x4){0.f, 0.f, 0.f, 0.f};
  conv_accumS(xpad, wkc1 + co_blk * (4 * 512), smem, c, acc);

  const int w = c.w0 + c.wl;
  const int wcase = (w == 0) ? 0 : ((w == 95) ? 2 : 1);
  _Float16* lt = (_Float16*)smem;                  // [256][68]
#pragma unroll
  for (int fa = 0; fa < 4; ++fa) {
    const int co_l = fa * 16 + c.quad * 4;
    float4 bs = *(const float4*)(bias_p + c.co_wg + co_l);
    const float4 b2 = *(const float4*)(bias_c1 + c.co_wg + co_l);
    bs.x += b2.x; bs.y += b2.y; bs.z += b2.z; bs.w += b2.w;
#pragma unroll
    for (int fb = 0; fb < 4; ++fb) {
      const int h = c.h0 + c.hl + fb;
      const int hcase = (h == 0) ? 0 : ((h == 95) ? 2 : 1);
      const float4 uq = *(const float4*)(u2 + ((size_t)(hcase * 8 + c.b) * 96 + w) * 256 + c.co_wg + co_l);
      const float4 vq = *(const float4*)(v2 + ((size_t)(wcase * 8 + c.b) * 96 + h) * 256 + c.co_wg + co_l);
      const int n_l = (c.hl + fb) * 16 + c.wl;
      f16x4v pk;
      pk[0] = (_Float16)fmaxf(acc[fa][fb][0] + bs.x + uq.x + vq.x, 0.f);
      pk[1] = (_Float16)fmaxf(acc[fa][fb][1] + bs.y + uq.y + vq.y, 0.f);
      pk[2] = (_Float16)fmaxf(acc[fa][fb][2] + bs.z + uq.z + vq.z, 0.f);
      pk[3] = (_Float16)fmaxf(acc[fa][fb][3] + bs.w + uq.w + vq.w, 0.f);
      *(f16x4v*)&lt[n_l * 68 + co_l] = pk;
    }
  }
  __syncthreads();
  _Float16* out_base = rpad + ((size_t)(c.b * HP + c.h0 + 1) * WP + c.w0 + 1) * 256;
  const int cc = threadIdx.x & 7, rr = threadIdx.x >> 3;
#pragma unroll
  for (int pass = 0; pass < 8; ++pass) {
    const int n_l = pass * 32 + rr;
    const int hh = n_l >> 4, ww = n_l & 15;
    uint2 q0 = *(const uint2*)&lt[n_l * 68 + cc * 8];
    uint2 q1 = *(const uint2*)&lt[n_l * 68 + cc * 8 + 4];
    *(uint4*)(out_base + (size_t)hh * (WP * 256) + ww * 256 + c.co_wg + cc * 8) =
        make_uint4(q0.x, q0.y, q1.x, q1.y);
  }
}

// ---------------- final conv, relu, NCHW f32 to d_out ---------------------
__global__ __launch_bounds__(256, 3) void k_conv_c2(
    const _Float16* __restrict__ rpad, const _Float16* __restrict__ wkc2,
    const float* __restrict__ bias, float* __restrict__ dout)
{
  __shared__ __align__(16) char smem[SMEM_BS];
  const int lin = blockIdx.x;
  const int co_blk = lin / 288, spatial = lin - co_blk * 288;
  CtxS c = make_ctxS(spatial, co_blk * 64);
  f32x4 acc[4][4];
#pragma unroll
  for (int i = 0; i < 4; ++i)
#pragma unroll
    for (int j = 0; j < 4; ++j) acc[i][j] = (f32x4){0.f, 0.f, 0.f, 0.f};
  conv_accumS(rpad, wkc2 + co_blk * (4 * 512), smem, c, acc);
#pragma unroll
  for (int fb = 0; fb < 4; ++fb) {
    const int h = c.h0 + c.hl + fb;
    const int w = c.w0 + c.wl;
    float* op = dout + (size_t)c.b * 2359296 + h * 96 + w;
#pragma unroll
    for (int fa = 0; fa < 4; ++fa) {
      const int co = c.co_wg + fa * 16 + c.quad * 4;
      const float4 bs = *(const float4*)(bias + co);
      op[(size_t)(co + 0) * 9216] = fmaxf(acc[fa][fb][0] + bs.x, 0.f);
      op[(size_t)(co + 1) * 9216] = fmaxf(acc[fa][fb][1] + bs.y, 0.f);
      op[(size_t)(co + 2) * 9216] = fmaxf(acc[fa][fb][2] + bs.z, 0.f);
      op[(size_t)(co + 3) * 9216] = fmaxf(acc[fa][fb][3] + bs.w, 0.f);
    }
  }
}

// ---------------- aux kernels ---------------------------------------------
// Zero the 1-px halo ring of x_pad (z=0) and r_pad (z=1). 388 border pos/img.
__global__ void k_border(_Float16* __restrict__ xpad, _Float16* __restrict__ rpad)
{
  const int idx = blockIdx.x, b = blockIdx.y;
  _Float16* buf = blockIdx.z ? rpad : xpad;
  int h, w;
  if (idx < 98)       { h = 0;  w = idx; }
  else if (idx < 196) { h = 97; w = idx - 98; }
  else { const int r = idx - 196; h = 1 + (r >> 1); w = (r & 1) ? 97 : 0; }
  buf[((size_t)(b * HP + h) * WP + w) * 256 + threadIdx.x] = (_Float16)0.f;
}

__global__ void k_pack_x(const float* __restrict__ x, _Float16* __restrict__ xpad)
{
  __shared__ float tile[32][33];
  const int bh = blockIdx.x;
  const int b = bh / 96, h = bh - b * 96;
  const int c0 = blockIdx.y * 32, w0 = blockIdx.z * 32;
  const int tx = threadIdx.x & 31, ty = threadIdx.x >> 5;
#pragma unroll
  for (int i = 0; i < 4; ++i) {
    int cI = c0 + ty + i * 8;
    tile[ty + i * 8][tx] = x[(((size_t)b * 256 + cI) * 96 + h) * 96 + w0 + tx];
  }
  __syncthreads();
#pragma unroll
  for (int i = 0; i < 4; ++i) {
    int w = w0 + ty + i * 8;
    xpad[((size_t)(b * HP + h + 1) * WP + (w + 1)) * 256 + c0 + tx] =
        (_Float16)tile[tx][ty + i * 8];
  }
}

// main conv weights -> tiled layout: idx = ((cb*9+tap)*16 + cog)*512 + m*32 + kk
__global__ void k_repack_w(const float* w0, const float* g0, const float* w1, const float* g1,
                           const float* w2, const float* g2, const float* w3, const float* g3,
                           const float* w4, const float* g4, _Float16* __restrict__ wk)
{
  const int set = blockIdx.y;
  const float* w; const float* g;
  switch (set) {
    case 0: w = w0; g = g0; break;
    case 1: w = w1; g = g1; break;
    case 2: w = w2; g = g2; break;
    case 3: w = w3; g = g3; break;
    default: w = w4; g = g4; break;
  }
  const int t = blockIdx.x * 256 + threadIdx.x;   // co*256 + ci
  const int co = t >> 8, ci = t & 255;
  const int cb = ci >> 5, kk = ci & 31, cog = co >> 4, m = co & 15;
  const float gv = g[co];
  const float* src = w + ((size_t)co * 256 + ci) * 9;
  _Float16* dst = wk + (size_t)set * WSET + cog * 512 + m * 32 + kk;
#pragma unroll
  for (int tap = 0; tap < 9; ++tap)
    dst[(cb * 9 + tap) * 8192] = (_Float16)(src[tap] * gv);
}

// case-summed 1D weights for U'/V'
__global__ void k_repack_uvw(const float* __restrict__ wp, const float* __restrict__ gp,
                             _Float16* __restrict__ wuv)
{
  const int tcs = blockIdx.y;                             // 0..5 = t*3+cs
  const int tt = tcs / 3, cs = tcs - tt * 3;
  const int idx = blockIdx.x * 256 + threadIdx.x;         // co*256 + ci
  const int co = idx >> 8, ci = idx & 255;
  const float gv = gp[co];
  const float* src = wp + ((size_t)co * 256 + ci) * 9;    // [dh][dw]
  const int lo = (cs == 0) ? 1 : 0, hi = (cs == 2) ? 1 : 2;
  _Float16* base = wuv + (size_t)tcs * WUV_SET;
#pragma unroll
  for (int d = 0; d < 3; ++d) {
    float s = 0.f;
    for (int e = lo; e <= hi; ++e)
      s += (tt == 0) ? src[e * 3 + d] : src[d * 3 + e];
    const int k = d * 256 + ci;
    const int kb = k >> 5, kk = k & 31;
    base[(size_t)(kb * 16 + (co >> 4)) * 512 + (co & 15) * 32 + kk] = (_Float16)(s * gv);
  }
}

// ---------------- launcher -------------------------------------------------
extern "C" void kernel_launch(void* const* d_in, const int* in_sizes, int n_in,
                              void* d_out, int out_size, void* d_ws, size_t ws_size,
                              hipStream_t stream)
{
  const float* x    = (const float*)d_in[0];
  const float* w_p1 = (const float*)d_in[1];
  const float* g_p1 = (const float*)d_in[2];
  const float* b_p1 = (const float*)d_in[3];
  const float* w_p2 = (const float*)d_in[4];
  const float* g_p2 = (const float*)d_in[5];
  const float* b_p2 = (const float*)d_in[6];
  const float* w_p  = (const float*)d_in[7];
  const float* g_p  = (const float*)d_in[8];
  const float* b_p  = (const float*)d_in[9];
  const float* w_c1 = (const float*)d_in[10];
  const float* g_c1 = (const float*)d_in[11];
  const float* b_c1 = (const float*)d_in[12];
  const float* w_c2 = (const float*)d_in[13];
  const float* g_c2 = (const float*)d_in[14];
  const float* b_c2 = (const float*)d_in[15];

  char* ws = (char*)d_ws;
  size_t off = 0;
  _Float16* x_pad = (_Float16*)(ws + off); off += XPAD_E * 2;
  _Float16* r_pad = (_Float16*)(ws + off); off += XPAD_E * 2;
  _Float16* wks   = (_Float16*)(ws + off); off += (size_t)5 * WSET * 2;
  _Float16* wuv   = (_Float16*)(ws + off); off += (size_t)6 * WUV_SET * 2;
  float*    u_pad = (float*)(ws + off);    off += UVP_E * 4;
  float*    v_pad = (float*)(ws + off);    off += UVP_E * 4;
  float*    u2    = (float*)(ws + off);    off += UV2_E * 4;
  float*    v2    = (float*)(ws + off);    off += UV2_E * 4;
  (void)ws_size; (void)in_sizes; (void)n_in; (void)out_size;

  hipMemsetAsync(u_pad, 0, UVP_E * 4, stream);     // atomicMax targets + zero pad
  hipMemsetAsync(v_pad, 0, UVP_E * 4, stream);

  k_border    <<<dim3(388, 8, 2), 256, 0, stream>>>(x_pad, r_pad);
  k_pack_x    <<<dim3(768, 8, 3), 256, 0, stream>>>(x, x_pad);
  k_repack_w  <<<dim3(256, 5),    256, 0, stream>>>(w_p1, g_p1, w_p2, g_p2, w_p, g_p,
                                                    w_c1, g_c1, w_c2, g_c2, wks);
  k_repack_uvw<<<dim3(256, 6),    256, 0, stream>>>(w_p, g_p, wuv);
  k_conv_p12  <<<1152, 256, 0, stream>>>(x_pad, wks, b_p1, b_p2, u_pad, v_pad);
  k_uv1d      <<<48,   256, 0, stream>>>(u_pad, v_pad, wuv, u2, v2);
  k_conv_c1f  <<<1152, 256, 0, stream>>>(x_pad, wks + (size_t)3 * WSET, b_p, b_c1,
                                         u2, v2, r_pad);
  k_conv_c2   <<<1152, 256, 0, stream>>>(r_pad, wks + (size_t)4 * WSET, b_c2,
                                         (float*)d_out);
}